// Round 1
// baseline (743.370 us; speedup 1.0000x reference)
//
#include <hip/hip_runtime.h>
#include <hip/hip_bf16.h>
#include <math.h>

#define B_ 2
#define S_ 2048
#define H_ 2048
#define NH_ 32
#define NKV_ 8
#define D_ 64
#define F_ 3072            // (NH + 2*NKV) * D
#define SCALE_ 0.125f      // 1/sqrt(64)

using bf16 = __bf16;
using bf16x4 = __attribute__((ext_vector_type(4))) __bf16;
using bf16x8 = __attribute__((ext_vector_type(8))) __bf16;
using f32x4 = __attribute__((ext_vector_type(4))) float;

#define GLOBAL_AS(p) ((__attribute__((address_space(1))) void*)(p))
#define LDS_AS(p)    ((__attribute__((address_space(3))) void*)(p))

// ---------------- fp32 -> bf16 convert (vectorized) ----------------
__global__ void cvt_f32_bf16(const float4* __restrict__ in, bf16* __restrict__ out, int n4) {
    int i = blockIdx.x * 256 + threadIdx.x;
    if (i >= n4) return;
    float4 v = in[i];
    bf16x4 o = {(bf16)v.x, (bf16)v.y, (bf16)v.z, (bf16)v.w};
    *reinterpret_cast<bf16x4*>(out + (size_t)i * 4) = o;
}

// ---------------- transpose + convert: in fp32 [K][N] -> out bf16 [N][K] ----------------
__global__ void transpose_to_bf16(const float* __restrict__ in, bf16* __restrict__ out,
                                  int K, int N) {
    __shared__ float tile[32][33];
    int n0 = blockIdx.x * 32, k0 = blockIdx.y * 32;
    int tx = threadIdx.x, ty = threadIdx.y;   // (32, 8)
#pragma unroll
    for (int i = 0; i < 4; ++i)
        tile[ty + i * 8][tx] = in[(size_t)(k0 + ty + i * 8) * N + n0 + tx];
    __syncthreads();
#pragma unroll
    for (int i = 0; i < 4; ++i)
        out[(size_t)(n0 + ty + i * 8) * K + k0 + tx] = (bf16)tile[tx][ty + i * 8];
}

// ---------------- bf16 MFMA GEMM: C[M][N] = A[M][K] * BT[N][K]^T, fp32 out ----------------
// 128x128 block tile, 4 waves (each 64x64), BK=32, global_load_lds width-16 staging.
__global__ __launch_bounds__(256) void gemm_bt(const bf16* __restrict__ A,
                                               const bf16* __restrict__ BT,
                                               float* __restrict__ C,
                                               int M, int N, int K) {
    __shared__ __attribute__((aligned(16))) bf16 As[128 * 32];
    __shared__ __attribute__((aligned(16))) bf16 Bs[128 * 32];
    const int tid = threadIdx.x;
    const int w = tid >> 6, lane = tid & 63;
    const int t = lane & 15, quad = lane >> 4;
    const int m0 = blockIdx.y * 128, n0 = blockIdx.x * 128;
    const int wm = (w >> 1) * 64, wn = (w & 1) * 64;
    const int lrow = lane >> 2;        // row within 16-row staging chunk
    const int lcol = (lane & 3) * 8;   // element offset within row (8 bf16 = 16B)

    f32x4 acc[4][4] = {};

    for (int k0 = 0; k0 < K; k0 += 32) {
#pragma unroll
        for (int i = 0; i < 2; ++i) {
            int c = w * 2 + i;  // chunk 0..7, 16 rows each
            const bf16* ga = A + (size_t)(m0 + c * 16 + lrow) * K + k0 + lcol;
            __builtin_amdgcn_global_load_lds(GLOBAL_AS(ga), LDS_AS(As + c * 512), 16, 0, 0);
            const bf16* gb = BT + (size_t)(n0 + c * 16 + lrow) * K + k0 + lcol;
            __builtin_amdgcn_global_load_lds(GLOBAL_AS(gb), LDS_AS(Bs + c * 512), 16, 0, 0);
        }
        __syncthreads();
        bf16x8 a[4], b[4];
#pragma unroll
        for (int i = 0; i < 4; ++i)
            a[i] = *reinterpret_cast<const bf16x8*>(As + (wm + i * 16 + t) * 32 + quad * 8);
#pragma unroll
        for (int j = 0; j < 4; ++j)
            b[j] = *reinterpret_cast<const bf16x8*>(Bs + (wn + j * 16 + t) * 32 + quad * 8);
#pragma unroll
        for (int i = 0; i < 4; ++i)
#pragma unroll
            for (int j = 0; j < 4; ++j)
                acc[i][j] = __builtin_amdgcn_mfma_f32_16x16x32_bf16(a[i], b[j], acc[i][j], 0, 0, 0);
        __syncthreads();
    }
    // epilogue: C/D layout col=lane&15, row=quad*4+r
#pragma unroll
    for (int i = 0; i < 4; ++i)
#pragma unroll
        for (int j = 0; j < 4; ++j)
#pragma unroll
            for (int r = 0; r < 4; ++r)
                C[(size_t)(m0 + wm + i * 16 + quad * 4 + r) * N + n0 + wn + j * 16 + t] =
                    acc[i][j][r];
}

// ---------------- RoPE (NeoX) + split qkv into Q / K / V^T bf16 layouts ----------------
// Q:  [B*NH][S][D]   K: [B*NKV][S][D]   Vt: [B*NKV][D][S]
__global__ void rope_split(const float* __restrict__ qkv, const int* __restrict__ positions,
                           bf16* __restrict__ Q, bf16* __restrict__ Kb, bf16* __restrict__ Vt) {
    int row = blockIdx.x;           // b*S + s
    int head = blockIdx.y;          // 0..NH+2*NKV-1
    int d = threadIdx.x;            // 0..63
    int s = row & (S_ - 1), b = row >> 11;
    const float* base = qkv + (size_t)row * F_;
    if (head < NH_ + NKV_) {
        int isK = head >= NH_;
        int hh = isK ? head - NH_ : head;
        int coloff = isK ? NH_ * D_ + hh * D_ : hh * D_;
        float x = base[coloff + d];
        int i = d & 31;
        float pos = (float)positions[s];
        float inv = __expf(-(float)i * (9.210340371976184f / 32.0f));  // 10000^(-i/32)
        float sn, cs;
        sincosf(pos * inv, &sn, &cs);
        float partner = (d < 32) ? base[coloff + d + 32] : base[coloff + d - 32];
        float sign = (d < 32) ? -1.0f : 1.0f;
        float o = x * cs + sign * partner * sn;
        if (!isK)
            Q[((size_t)(b * NH_ + hh) * S_ + s) * D_ + d] = (bf16)o;
        else
            Kb[((size_t)(b * NKV_ + hh) * S_ + s) * D_ + d] = (bf16)o;
    } else {
        int hv = head - NH_ - NKV_;
        float v = base[NH_ * D_ + NKV_ * D_ + hv * D_ + d];
        Vt[((size_t)(b * NKV_ + hv) * D_ + d) * S_ + s] = (bf16)v;
    }
}

// ---------------- causal GQA flash attention (MFMA, per-wave 16-row Q tile) ----------------
__global__ __launch_bounds__(256) void flash_attn(const bf16* __restrict__ Q,
                                                  const bf16* __restrict__ Kb,
                                                  const bf16* __restrict__ Vt,
                                                  bf16* __restrict__ ctx) {
    __shared__ __attribute__((aligned(16))) bf16 Plds[4][16 * 32];
    int tid = threadIdx.x;
    int w = tid >> 6, lane = tid & 63;
    int t = lane & 15, quad = lane >> 4;
    int q0 = blockIdx.x * 64 + w * 16;
    int h = blockIdx.y, b = blockIdx.z;
    int bh = b * NH_ + h;
    int bhk = b * NKV_ + (h >> 2);   // GQA group of 4

    const bf16* Qp = Q + ((size_t)bh * S_ + q0) * D_;
    bf16x8 qf0 = *reinterpret_cast<const bf16x8*>(Qp + t * D_ + quad * 8);
    bf16x8 qf1 = *reinterpret_cast<const bf16x8*>(Qp + t * D_ + 32 + quad * 8);

    f32x4 o[4] = {};
    float m[4] = {-1e30f, -1e30f, -1e30f, -1e30f};
    float l[4] = {0.f, 0.f, 0.f, 0.f};
    const bf16* Kbase = Kb + (size_t)bhk * S_ * D_;
    const bf16* Vbase = Vt + (size_t)bhk * D_ * S_;

    for (int k0 = 0; k0 < q0 + 16; k0 += 32) {
        f32x4 sa[2] = {};
#pragma unroll
        for (int nt = 0; nt < 2; ++nt) {
            const bf16* Kp = Kbase + (size_t)(k0 + nt * 16 + t) * D_;
            bf16x8 kf0 = *reinterpret_cast<const bf16x8*>(Kp + quad * 8);
            bf16x8 kf1 = *reinterpret_cast<const bf16x8*>(Kp + 32 + quad * 8);
            sa[nt] = __builtin_amdgcn_mfma_f32_16x16x32_bf16(qf0, kf0, sa[nt], 0, 0, 0);
            sa[nt] = __builtin_amdgcn_mfma_f32_16x16x32_bf16(qf1, kf1, sa[nt], 0, 0, 0);
        }
        // scale + causal mask; C layout: col=key (t within n-tile), row=q0+quad*4+r
        float p[2][4], mx[4];
#pragma unroll
        for (int r = 0; r < 4; ++r) {
            int qrow = q0 + quad * 4 + r;
            float s0 = (k0 + t <= qrow) ? sa[0][r] * SCALE_ : -1e30f;
            float s1 = (k0 + 16 + t <= qrow) ? sa[1][r] * SCALE_ : -1e30f;
            p[0][r] = s0;
            p[1][r] = s1;
            mx[r] = fmaxf(s0, s1);
        }
#pragma unroll
        for (int mask = 1; mask < 16; mask <<= 1)
#pragma unroll
            for (int r = 0; r < 4; ++r)
                mx[r] = fmaxf(mx[r], __shfl_xor(mx[r], mask, 64));
        float alpha[4], rs[4];
#pragma unroll
        for (int r = 0; r < 4; ++r) {
            float mn = fmaxf(m[r], mx[r]);
            alpha[r] = __expf(m[r] - mn);
            m[r] = mn;
            p[0][r] = __expf(p[0][r] - mn);
            p[1][r] = __expf(p[1][r] - mn);
            rs[r] = p[0][r] + p[1][r];
        }
#pragma unroll
        for (int mask = 1; mask < 16; mask <<= 1)
#pragma unroll
            for (int r = 0; r < 4; ++r)
                rs[r] += __shfl_xor(rs[r], mask, 64);
#pragma unroll
        for (int r = 0; r < 4; ++r)
            l[r] = l[r] * alpha[r] + rs[r];
#pragma unroll
        for (int dt = 0; dt < 4; ++dt)
#pragma unroll
            for (int r = 0; r < 4; ++r)
                o[dt][r] *= alpha[r];
        // P: C-layout -> LDS -> A-layout (A[m=lane&15][k=quad*8+j])
#pragma unroll
        for (int nt = 0; nt < 2; ++nt)
#pragma unroll
            for (int r = 0; r < 4; ++r)
                Plds[w][(quad * 4 + r) * 32 + nt * 16 + t] = (bf16)p[nt][r];
        asm volatile("s_waitcnt lgkmcnt(0)" ::: "memory");
        bf16x8 pf = *reinterpret_cast<const bf16x8*>(&Plds[w][t * 32 + quad * 8]);
        asm volatile("" ::: "memory");
#pragma unroll
        for (int dt = 0; dt < 4; ++dt) {
            const bf16* Vp = Vbase + (size_t)(dt * 16 + t) * S_ + k0 + quad * 8;
            bf16x8 vf = *reinterpret_cast<const bf16x8*>(Vp);
            o[dt] = __builtin_amdgcn_mfma_f32_16x16x32_bf16(pf, vf, o[dt], 0, 0, 0);
        }
    }
    // write ctx [B*S][NH*D] bf16
#pragma unroll
    for (int r = 0; r < 4; ++r) {
        float inv = 1.0f / l[r];
        int row = b * S_ + q0 + quad * 4 + r;
#pragma unroll
        for (int dt = 0; dt < 4; ++dt)
            ctx[(size_t)row * (NH_ * D_) + h * D_ + dt * 16 + t] = (bf16)(o[dt][r] * inv);
    }
}

extern "C" void kernel_launch(void* const* d_in, const int* in_sizes, int n_in,
                              void* d_out, int out_size, void* d_ws, size_t ws_size,
                              hipStream_t stream) {
    const int* positions = (const int*)d_in[0];
    const float* hidden = (const float*)d_in[1];
    const float* Wqkv = (const float*)d_in[2];
    const float* Wo = (const float*)d_in[3];
    float* out = (float*)d_out;

    char* ws = (char*)d_ws;
    size_t off = 0;
    auto carve = [&](size_t bytes) {
        void* p = ws + off;
        off += (bytes + 255) & ~(size_t)255;
        return p;
    };
    bf16* hidB = (bf16*)carve((size_t)B_ * S_ * H_ * 2);
    bf16* WqkvT = (bf16*)carve((size_t)F_ * H_ * 2);
    bf16* WoT = (bf16*)carve((size_t)H_ * H_ * 2);
    float* qkv = (float*)carve((size_t)B_ * S_ * F_ * 4);
    bf16* Qb = (bf16*)carve((size_t)B_ * NH_ * S_ * D_ * 2);
    bf16* Kbb = (bf16*)carve((size_t)B_ * NKV_ * S_ * D_ * 2);
    bf16* Vt = (bf16*)carve((size_t)B_ * NKV_ * S_ * D_ * 2);
    bf16* ctx = (bf16*)carve((size_t)B_ * S_ * NH_ * D_ * 2);

    cvt_f32_bf16<<<(B_ * S_ * H_ / 4 + 255) / 256, 256, 0, stream>>>((const float4*)hidden, hidB,
                                                                     B_ * S_ * H_ / 4);
    transpose_to_bf16<<<dim3(F_ / 32, H_ / 32), dim3(32, 8), 0, stream>>>(Wqkv, WqkvT, H_, F_);
    transpose_to_bf16<<<dim3(H_ / 32, H_ / 32), dim3(32, 8), 0, stream>>>(Wo, WoT, H_, H_);
    gemm_bt<<<dim3(F_ / 128, (B_ * S_) / 128), 256, 0, stream>>>(hidB, WqkvT, qkv, B_ * S_, F_, H_);
    rope_split<<<dim3(B_ * S_, NH_ + 2 * NKV_), 64, 0, stream>>>(qkv, positions, Qb, Kbb, Vt);
    flash_attn<<<dim3(S_ / 64, NH_, B_), 256, 0, stream>>>(Qb, Kbb, Vt, ctx);
    gemm_bt<<<dim3(H_ / 128, (B_ * S_) / 128), 256, 0, stream>>>(ctx, WoT, out, B_ * S_, H_, H_);
}

// Round 2
// 533.878 us; speedup vs baseline: 1.3924x; 1.3924x over previous
//
#include <hip/hip_runtime.h>
#include <hip/hip_bf16.h>
#include <math.h>

#define B_ 2
#define S_ 2048
#define H_ 2048
#define NH_ 32
#define NKV_ 8
#define D_ 64
#define F_ 3072            // (NH + 2*NKV) * D
#define SCALE_ 0.125f      // 1/sqrt(64)

using bf16 = __bf16;
using bf16x4 = __attribute__((ext_vector_type(4))) __bf16;
using bf16x8 = __attribute__((ext_vector_type(8))) __bf16;
using f32x4 = __attribute__((ext_vector_type(4))) float;

#define GLOBAL_AS(p) ((__attribute__((address_space(1))) void*)(p))
#define LDS_AS(p)    ((__attribute__((address_space(3))) void*)(p))

// ---------------- fp32 -> bf16 convert (vectorized) ----------------
__global__ void cvt_f32_bf16(const float4* __restrict__ in, bf16* __restrict__ out, int n4) {
    int i = blockIdx.x * 256 + threadIdx.x;
    if (i >= n4) return;
    float4 v = in[i];
    bf16x4 o = {(bf16)v.x, (bf16)v.y, (bf16)v.z, (bf16)v.w};
    *reinterpret_cast<bf16x4*>(out + (size_t)i * 4) = o;
}

// ---------------- transpose + convert: in fp32 [K][N] -> out bf16 [N][K] ----------------
__global__ void transpose_to_bf16(const float* __restrict__ in, bf16* __restrict__ out,
                                  int K, int N) {
    __shared__ float tile[32][33];
    int n0 = blockIdx.x * 32, k0 = blockIdx.y * 32;
    int tx = threadIdx.x, ty = threadIdx.y;   // (32, 8)
#pragma unroll
    for (int i = 0; i < 4; ++i)
        tile[ty + i * 8][tx] = in[(size_t)(k0 + ty + i * 8) * N + n0 + tx];
    __syncthreads();
#pragma unroll
    for (int i = 0; i < 4; ++i)
        out[(size_t)(n0 + ty + i * 8) * K + k0 + tx] = (bf16)tile[tx][ty + i * 8];
}

// ---------------- bf16 MFMA GEMM: C[M][N] = A[M][K] * BT[N][K]^T, fp32 out ----------------
__global__ __launch_bounds__(256) void gemm_bt(const bf16* __restrict__ A,
                                               const bf16* __restrict__ BT,
                                               float* __restrict__ C,
                                               int M, int N, int K) {
    __shared__ __attribute__((aligned(16))) bf16 As[128 * 32];
    __shared__ __attribute__((aligned(16))) bf16 Bs[128 * 32];
    const int tid = threadIdx.x;
    const int w = tid >> 6, lane = tid & 63;
    const int t = lane & 15, quad = lane >> 4;
    const int m0 = blockIdx.y * 128, n0 = blockIdx.x * 128;
    const int wm = (w >> 1) * 64, wn = (w & 1) * 64;
    const int lrow = lane >> 2;
    const int lcol = (lane & 3) * 8;

    f32x4 acc[4][4] = {};

    for (int k0 = 0; k0 < K; k0 += 32) {
#pragma unroll
        for (int i = 0; i < 2; ++i) {
            int c = w * 2 + i;
            const bf16* ga = A + (size_t)(m0 + c * 16 + lrow) * K + k0 + lcol;
            __builtin_amdgcn_global_load_lds(GLOBAL_AS(ga), LDS_AS(As + c * 512), 16, 0, 0);
            const bf16* gb = BT + (size_t)(n0 + c * 16 + lrow) * K + k0 + lcol;
            __builtin_amdgcn_global_load_lds(GLOBAL_AS(gb), LDS_AS(Bs + c * 512), 16, 0, 0);
        }
        __syncthreads();
        bf16x8 a[4], b[4];
#pragma unroll
        for (int i = 0; i < 4; ++i)
            a[i] = *reinterpret_cast<const bf16x8*>(As + (wm + i * 16 + t) * 32 + quad * 8);
#pragma unroll
        for (int j = 0; j < 4; ++j)
            b[j] = *reinterpret_cast<const bf16x8*>(Bs + (wn + j * 16 + t) * 32 + quad * 8);
#pragma unroll
        for (int i = 0; i < 4; ++i)
#pragma unroll
            for (int j = 0; j < 4; ++j)
                acc[i][j] = __builtin_amdgcn_mfma_f32_16x16x32_bf16(a[i], b[j], acc[i][j], 0, 0, 0);
        __syncthreads();
    }
#pragma unroll
    for (int i = 0; i < 4; ++i)
#pragma unroll
        for (int j = 0; j < 4; ++j)
#pragma unroll
            for (int r = 0; r < 4; ++r)
                C[(size_t)(m0 + wm + i * 16 + quad * 4 + r) * N + n0 + wn + j * 16 + t] =
                    acc[i][j][r];
}

// ---------------- RoPE (NeoX) + split; Q pre-scaled by SCALE ----------------
// Q:  [B*NH][S][D]   K: [B*NKV][S][D]   Vt: [B*NKV][D][S]
__global__ void rope_split(const float* __restrict__ qkv, const int* __restrict__ positions,
                           bf16* __restrict__ Q, bf16* __restrict__ Kb, bf16* __restrict__ Vt) {
    int row = blockIdx.x;           // b*S + s
    int head = blockIdx.y;
    int d = threadIdx.x;            // 0..63
    int s = row & (S_ - 1), b = row >> 11;
    const float* base = qkv + (size_t)row * F_;
    if (head < NH_ + NKV_) {
        int isK = head >= NH_;
        int hh = isK ? head - NH_ : head;
        int coloff = isK ? NH_ * D_ + hh * D_ : hh * D_;
        float x = base[coloff + d];
        int i = d & 31;
        float pos = (float)positions[s];
        float inv = __expf(-(float)i * (9.210340371976184f / 32.0f));  // 10000^(-i/32)
        float sn, cs;
        sincosf(pos * inv, &sn, &cs);
        float partner = (d < 32) ? base[coloff + d + 32] : base[coloff + d - 32];
        float sign = (d < 32) ? -1.0f : 1.0f;
        float o = x * cs + sign * partner * sn;
        if (!isK)
            Q[((size_t)(b * NH_ + hh) * S_ + s) * D_ + d] = (bf16)(o * SCALE_);
        else
            Kb[((size_t)(b * NKV_ + hh) * S_ + s) * D_ + d] = (bf16)o;
    } else {
        int hv = head - NH_ - NKV_;
        float v = base[NH_ * D_ + NKV_ * D_ + hv * D_ + d];
        Vt[((size_t)(b * NKV_ + hv) * D_ + d) * S_ + s] = (bf16)v;
    }
}

// ---------------- causal GQA flash attention, S^T formulation ----------------
// One wave per block; wave handles Q-tiles (i) and (127-i) for causal balance.
// S^T = K*Q^T: C-layout gives row=key(quad*4+r), col=q(t). Softmax row state is
// per-lane scalar; reductions are 2 shfl_xor (masks 16,32).
__global__ __launch_bounds__(64, 4) void flash_attn(const bf16* __restrict__ Q,
                                                    const bf16* __restrict__ Kb,
                                                    const bf16* __restrict__ Vt,
                                                    bf16* __restrict__ ctx) {
    __shared__ __attribute__((aligned(16))) bf16 Plds[16 * 72];  // [q][64 keys + 8 pad]
    const int lane = threadIdx.x;
    const int t = lane & 15, quad = lane >> 4;
    const int h = blockIdx.y, b = blockIdx.z;
    const int bh = b * NH_ + h;
    const int bhk = b * NKV_ + (h >> 2);
    const bf16* Kbase = Kb + (size_t)bhk * S_ * D_;
    const bf16* Vbase = Vt + (size_t)bhk * D_ * S_;

#pragma unroll
    for (int rep = 0; rep < 2; ++rep) {
        const int tileIdx = rep ? (127 - (int)blockIdx.x) : (int)blockIdx.x;
        const int qbase = tileIdx * 16;
        const int kend = qbase + 16;
        const int nch = (kend + 63) >> 6;

        const bf16* Qp = Q + ((size_t)bh * S_ + qbase) * D_;
        bf16x8 qf0 = *reinterpret_cast<const bf16x8*>(Qp + t * D_ + quad * 8);
        bf16x8 qf1 = *reinterpret_cast<const bf16x8*>(Qp + t * D_ + 32 + quad * 8);

        f32x4 o[4] = {};
        float m = -1e30f, l = 0.f;

        bf16x8 kf[4][2];
#pragma unroll
        for (int tl = 0; tl < 4; ++tl)
#pragma unroll
            for (int hf = 0; hf < 2; ++hf)
                kf[tl][hf] = *reinterpret_cast<const bf16x8*>(
                    Kbase + (size_t)(tl * 16 + t) * D_ + hf * 32 + quad * 8);

        for (int c = 0; c < nch; ++c) {
            const int k0 = c << 6;
            // V frags for current chunk (independent of softmax; issue early)
            bf16x8 vf[4][2];
#pragma unroll
            for (int dt = 0; dt < 4; ++dt)
#pragma unroll
                for (int hf = 0; hf < 2; ++hf)
                    vf[dt][hf] = *reinterpret_cast<const bf16x8*>(
                        Vbase + (size_t)(dt * 16 + t) * S_ + k0 + hf * 32 + quad * 8);

            f32x4 sa[4] = {};
#pragma unroll
            for (int tl = 0; tl < 4; ++tl) {
                sa[tl] = __builtin_amdgcn_mfma_f32_16x16x32_bf16(kf[tl][0], qf0, sa[tl], 0, 0, 0);
                sa[tl] = __builtin_amdgcn_mfma_f32_16x16x32_bf16(kf[tl][1], qf1, sa[tl], 0, 0, 0);
            }
            // prefetch next chunk's K frags (regs just consumed by the MFMAs)
            if (c + 1 < nch) {
                const int kn = k0 + 64;
#pragma unroll
                for (int tl = 0; tl < 4; ++tl)
#pragma unroll
                    for (int hf = 0; hf < 2; ++hf)
                        kf[tl][hf] = *reinterpret_cast<const bf16x8*>(
                            Kbase + (size_t)(kn + tl * 16 + t) * D_ + hf * 32 + quad * 8);
            }
            // causal mask: only last chunk touches the diagonal
            if (c == nch - 1) {
                const int qrow = qbase + t;
#pragma unroll
                for (int tl = 0; tl < 4; ++tl)
#pragma unroll
                    for (int r = 0; r < 4; ++r)
                        if (k0 + tl * 16 + quad * 4 + r > qrow) sa[tl][r] = -1e30f;
            }
            // online softmax over 64 keys; row = q = t
            float mx = -1e30f;
#pragma unroll
            for (int tl = 0; tl < 4; ++tl)
#pragma unroll
                for (int r = 0; r < 4; ++r) mx = fmaxf(mx, sa[tl][r]);
            mx = fmaxf(mx, __shfl_xor(mx, 16, 64));
            mx = fmaxf(mx, __shfl_xor(mx, 32, 64));
            const float mn = fmaxf(m, mx);
            const float alpha = __expf(m - mn);
            m = mn;
            float rs = 0.f;
#pragma unroll
            for (int tl = 0; tl < 4; ++tl) {
                float p0 = __expf(sa[tl][0] - mn);
                float p1 = __expf(sa[tl][1] - mn);
                float p2 = __expf(sa[tl][2] - mn);
                float p3 = __expf(sa[tl][3] - mn);
                rs += (p0 + p1) + (p2 + p3);
                bf16x4 pk = {(bf16)p0, (bf16)p1, (bf16)p2, (bf16)p3};
                *reinterpret_cast<bf16x4*>(&Plds[t * 72 + tl * 16 + quad * 4]) = pk;
            }
#pragma unroll
            for (int dt = 0; dt < 4; ++dt)
#pragma unroll
                for (int r = 0; r < 4; ++r) o[dt][r] *= alpha;
            rs += __shfl_xor(rs, 16, 64);
            rs += __shfl_xor(rs, 32, 64);
            l = l * alpha + rs;

            asm volatile("s_waitcnt lgkmcnt(0)" ::: "memory");
            bf16x8 pf0 = *reinterpret_cast<const bf16x8*>(&Plds[t * 72 + quad * 8]);
            bf16x8 pf1 = *reinterpret_cast<const bf16x8*>(&Plds[t * 72 + 32 + quad * 8]);
#pragma unroll
            for (int dt = 0; dt < 4; ++dt) {
                o[dt] = __builtin_amdgcn_mfma_f32_16x16x32_bf16(vf[dt][0], pf0, o[dt], 0, 0, 0);
                o[dt] = __builtin_amdgcn_mfma_f32_16x16x32_bf16(vf[dt][1], pf1, o[dt], 0, 0, 0);
            }
        }
        // O^T C-layout: lane holds q=t, d=dt*16+quad*4+r -> 8B packed stores
        const float inv = 1.0f / l;
        const size_t row = (size_t)b * S_ + qbase + t;
#pragma unroll
        for (int dt = 0; dt < 4; ++dt) {
            bf16x4 ov = {(bf16)(o[dt][0] * inv), (bf16)(o[dt][1] * inv),
                         (bf16)(o[dt][2] * inv), (bf16)(o[dt][3] * inv)};
            *reinterpret_cast<bf16x4*>(ctx + row * (NH_ * D_) + h * D_ + dt * 16 + quad * 4) = ov;
        }
    }
}

extern "C" void kernel_launch(void* const* d_in, const int* in_sizes, int n_in,
                              void* d_out, int out_size, void* d_ws, size_t ws_size,
                              hipStream_t stream) {
    const int* positions = (const int*)d_in[0];
    const float* hidden = (const float*)d_in[1];
    const float* Wqkv = (const float*)d_in[2];
    const float* Wo = (const float*)d_in[3];
    float* out = (float*)d_out;

    char* ws = (char*)d_ws;
    size_t off = 0;
    auto carve = [&](size_t bytes) {
        void* p = ws + off;
        off += (bytes + 255) & ~(size_t)255;
        return p;
    };
    bf16* hidB = (bf16*)carve((size_t)B_ * S_ * H_ * 2);
    bf16* WqkvT = (bf16*)carve((size_t)F_ * H_ * 2);
    bf16* WoT = (bf16*)carve((size_t)H_ * H_ * 2);
    float* qkv = (float*)carve((size_t)B_ * S_ * F_ * 4);
    bf16* Qb = (bf16*)carve((size_t)B_ * NH_ * S_ * D_ * 2);
    bf16* Kbb = (bf16*)carve((size_t)B_ * NKV_ * S_ * D_ * 2);
    bf16* Vt = (bf16*)carve((size_t)B_ * NKV_ * S_ * D_ * 2);
    bf16* ctx = (bf16*)carve((size_t)B_ * S_ * NH_ * D_ * 2);

    cvt_f32_bf16<<<(B_ * S_ * H_ / 4 + 255) / 256, 256, 0, stream>>>((const float4*)hidden, hidB,
                                                                     B_ * S_ * H_ / 4);
    transpose_to_bf16<<<dim3(F_ / 32, H_ / 32), dim3(32, 8), 0, stream>>>(Wqkv, WqkvT, H_, F_);
    transpose_to_bf16<<<dim3(H_ / 32, H_ / 32), dim3(32, 8), 0, stream>>>(Wo, WoT, H_, H_);
    gemm_bt<<<dim3(F_ / 128, (B_ * S_) / 128), 256, 0, stream>>>(hidB, WqkvT, qkv, B_ * S_, F_, H_);
    rope_split<<<dim3(B_ * S_, NH_ + 2 * NKV_), 64, 0, stream>>>(qkv, positions, Qb, Kbb, Vt);
    flash_attn<<<dim3(64, NH_, B_), 64, 0, stream>>>(Qb, Kbb, Vt, ctx);
    gemm_bt<<<dim3(H_ / 128, (B_ * S_) / 128), 256, 0, stream>>>(ctx, WoT, out, B_ * S_, H_, H_);
}